// Round 2
// baseline (2681.943 us; speedup 1.0000x reference)
//
#include <hip/hip_runtime.h>
#include <stdint.h>

#define BATCH    32768
#define NE       8192
#define DIM      256
#define LOSS_OFF 8388608   // 32768*256
#define IDX_OFF  8388609

// async global->LDS, 16B per lane, LDS dest = wave-uniform base + lane*16
#define GLOAD_LDS16(g, l) __builtin_amdgcn_global_load_lds( \
    (const __attribute__((address_space(1))) void*)(g),     \
    (__attribute__((address_space(3))) void*)(l), 16, 0, 0)

// ---------------- kernel 1: row norms + loss zero ----------------
__global__ __launch_bounds__(256) void vq_norms(
    const float* __restrict__ x, const float* __restrict__ c,
    float* __restrict__ cn, float* __restrict__ xn, float* __restrict__ out) {
  const int w = threadIdx.x >> 6, lane = threadIdx.x & 63;
  const int row = blockIdx.x * 4 + w;              // [0, NE+BATCH)
  const float* src = (row < NE) ? (c + (size_t)row * DIM)
                                : (x + (size_t)(row - NE) * DIM);
  float4 v = *(const float4*)(src + (lane << 2));  // 64 lanes * 4 = 256
  float s = v.x * v.x + v.y * v.y + v.z * v.z + v.w * v.w;
  #pragma unroll
  for (int off = 32; off > 0; off >>= 1) s += __shfl_down(s, off);
  if (lane == 0) {
    if (row < NE) cn[row] = s; else xn[row - NE] = s;
  }
  if (row == 0 && lane == 0) out[LOSS_OFF] = 0.0f;
}

// ---------------- kernel 2: fused distance + argmin ----------------
// 256 blocks, 256 threads. Block owns 128 rows; loops all 8192 centroids
// in tiles of 128, K in chunks of 64 floats (16 float4 slots).
// LDS tiles stored [row][16 float4-slots], slot kq stored at position
// kq ^ ((row>>3)&7)  (source-side swizzle so global_load_lds stays linear).
__global__ __launch_bounds__(256) void vq_argmin(
    const float* __restrict__ x, const float* __restrict__ c,
    const float* __restrict__ xn, const float* __restrict__ cn,
    int* __restrict__ bestIdx) {
  __shared__ float xs[128 * 64];   // 32 KB
  __shared__ float cs[128 * 64];   // 32 KB

  const int tid  = threadIdx.x;
  const int w    = tid >> 6, lane = tid & 63;
  const int lrow = lane >> 4, lq = lane & 15;
  const int ty   = tid >> 4, tx = tid & 15;
  const int ty8  = ty << 3, tx8 = tx << 3;
  const int rowBase = blockIdx.x * 128;

  float xnr[8];
  #pragma unroll
  for (int i = 0; i < 8; ++i) xnr[i] = xn[rowBase + ty8 + i];

  float best[8]; int bidx[8];
  #pragma unroll
  for (int i = 0; i < 8; ++i) { best[i] = 3.4e38f; bidx[i] = 0; }

  for (int ct = 0; ct < NE / 128; ++ct) {
    float acc[8][8];
    #pragma unroll
    for (int i = 0; i < 8; ++i)
      #pragma unroll
      for (int j = 0; j < 8; ++j) acc[i][j] = 0.0f;

    for (int kc = 0; kc < 4; ++kc) {
      __syncthreads();   // previous chunk's reads done before overwrite
      #pragma unroll
      for (int i = 0; i < 8; ++i) {
        const int seg = i * 4 + w;          // 0..31, wave-uniform
        const int row = (seg << 2) + lrow;  // 0..127 (per-lane)
        const int swz = (row >> 3) & 7;
        // x tile
        GLOAD_LDS16(x + (size_t)(rowBase + row) * DIM + kc * 64 + ((lq ^ swz) << 2),
                    &xs[seg << 8]);
        // c tile
        GLOAD_LDS16(c + (size_t)(ct * 128 + row) * DIM + kc * 64 + ((lq ^ swz) << 2),
                    &cs[seg << 8]);
      }
      __syncthreads();   // compiler drains vmcnt(0) before s_barrier

      #pragma unroll 2
      for (int kq = 0; kq < 16; ++kq) {
        const int xo = (kq ^ (ty & 7)) << 2;   // row>>3 == ty for our 8 rows
        const int co = (kq ^ (tx & 7)) << 2;
        float4 xv[8], cv[8];
        #pragma unroll
        for (int i = 0; i < 8; ++i)
          xv[i] = *(const float4*)&xs[(ty8 + i) * 64 + xo];
        #pragma unroll
        for (int j = 0; j < 8; ++j)
          cv[j] = *(const float4*)&cs[(tx8 + j) * 64 + co];
        #pragma unroll
        for (int i = 0; i < 8; ++i)
          #pragma unroll
          for (int j = 0; j < 8; ++j) {
            acc[i][j] = fmaf(xv[i].x, cv[j].x, acc[i][j]);
            acc[i][j] = fmaf(xv[i].y, cv[j].y, acc[i][j]);
            acc[i][j] = fmaf(xv[i].z, cv[j].z, acc[i][j]);
            acc[i][j] = fmaf(xv[i].w, cv[j].w, acc[i][j]);
          }
      }
    }

    // distances + running argmin (strict < : earlier/lower index wins ties)
    float cnc[8];
    #pragma unroll
    for (int j = 0; j < 8; ++j) cnc[j] = cn[ct * 128 + tx8 + j];
    #pragma unroll
    for (int i = 0; i < 8; ++i)
      #pragma unroll
      for (int j = 0; j < 8; ++j) {
        const float d = (xnr[i] + cnc[j]) - 2.0f * acc[i][j];
        if (d < best[i]) { best[i] = d; bidx[i] = ct * 128 + tx8 + j; }
      }
  }

  // cross-thread (tx) reduction per row, explicit lowest-index tie-break
  __syncthreads();
  float* rd = xs;               // [128][16]
  int*   ri = (int*)cs;         // [128][16]
  #pragma unroll
  for (int i = 0; i < 8; ++i) {
    rd[(ty8 + i) * 16 + tx] = best[i];
    ri[(ty8 + i) * 16 + tx] = bidx[i];
  }
  __syncthreads();
  if (tid < 128) {
    float b = 3.4e38f; int bi = NE;
    for (int t = 0; t < 16; ++t) {
      const float d = rd[tid * 16 + t];
      const int  id = ri[tid * 16 + t];
      if (d < b || (d == b && id < bi)) { b = d; bi = id; }
    }
    bestIdx[rowBase + tid] = bi;
  }
}

// ---------------- kernel 3: gather + loss + index output ----------------
__global__ __launch_bounds__(256) void vq_gather(
    const float* __restrict__ x, const float* __restrict__ c,
    const int* __restrict__ bestIdx, float* __restrict__ out) {
  const int w = threadIdx.x >> 6, lane = threadIdx.x & 63;
  const int row = blockIdx.x * 4 + w;
  const int idx = bestIdx[row];
  const float4 q = *(const float4*)(c + (size_t)idx * DIM + (lane << 2));
  const float4 v = *(const float4*)(x + (size_t)row * DIM + (lane << 2));
  *(float4*)(out + (size_t)row * DIM + (lane << 2)) = q;  // x_q_out == x_q
  const float dx = q.x - v.x, dy = q.y - v.y, dz = q.z - v.z, dw = q.w - v.w;
  float s = dx * dx + dy * dy + dz * dz + dw * dw;
  #pragma unroll
  for (int off = 32; off > 0; off >>= 1) s += __shfl_down(s, off);
  if (lane == 0) {
    // loss = codebook + BETA*commitment = 1.25 * mean((x_q - x)^2)
    atomicAdd(&out[LOSS_OFF], s * (1.25f / 8388608.0f));
    out[IDX_OFF + row] = (float)idx;   // harness reads d_out as f32
  }
}

extern "C" void kernel_launch(void* const* d_in, const int* in_sizes, int n_in,
                              void* d_out, int out_size, void* d_ws, size_t ws_size,
                              hipStream_t stream) {
  const float* x = (const float*)d_in[0];
  const float* c = (const float*)d_in[1];
  float* out = (float*)d_out;
  float* cn = (float*)d_ws;            // [NE]
  float* xn = cn + NE;                 // [BATCH]
  int*  bestIdx = (int*)(xn + BATCH);  // [BATCH]

  vq_norms <<<(NE + BATCH) / 4, 256, 0, stream>>>(x, c, cn, xn, out);
  vq_argmin<<<BATCH / 128,     256, 0, stream>>>(x, c, xn, cn, bestIdx);
  vq_gather<<<BATCH / 4,       256, 0, stream>>>(x, c, bestIdx, out);
}

// Round 3
// 1137.652 us; speedup vs baseline: 2.3574x; 2.3574x over previous
//
#include <hip/hip_runtime.h>
#include <hip/hip_fp16.h>
#include <stdint.h>

#define BATCH 32768
#define NE    8192
#define DIM   256
#define KP    512            // packed [hi(256) | slo(256)] halves per row
#define LOSS_OFF 8388608     // 32768*256
#define IDX_OFF  8388609
#define LO_SCALE 2048.0f

typedef _Float16 v8h  __attribute__((ext_vector_type(8)));
typedef _Float16 v4h  __attribute__((ext_vector_type(4)));
typedef float    f32x4 __attribute__((ext_vector_type(4)));

// async global->LDS, 16B per lane; LDS dest = wave-uniform base + lane*16
#define GLOAD_LDS16(g, l) __builtin_amdgcn_global_load_lds( \
    (const __attribute__((address_space(1))) void*)(g),     \
    (__attribute__((address_space(3))) void*)(l), 16, 0, 0)

// ---- ws layout (bytes) ----
// Ax  f16 [BATCH][512]  @ 0          (33554432)
// Bc  f16 [NE][512]     @ 33554432   (8388608)
// cn  f32 [NE]          @ 41943040   (32768)
// part u64 [BATCH]      @ 41975808   (262144)   total ~40.3 MB

// ---------------- prep: x -> hi|slo, init partial/loss ----------------
__global__ __launch_bounds__(256) void vq_prep_x(
    const float* __restrict__ x, _Float16* __restrict__ Ax,
    unsigned long long* __restrict__ partial, float* __restrict__ out) {
  const int w = threadIdx.x >> 6, lane = threadIdx.x & 63;
  const int row = blockIdx.x * 4 + w;
  const float4 v = *(const float4*)(x + (size_t)row * DIM + (lane << 2));
  v4h h = { (_Float16)v.x, (_Float16)v.y, (_Float16)v.z, (_Float16)v.w };
  v4h l = { (_Float16)((v.x - (float)h[0]) * LO_SCALE),
            (_Float16)((v.y - (float)h[1]) * LO_SCALE),
            (_Float16)((v.z - (float)h[2]) * LO_SCALE),
            (_Float16)((v.w - (float)h[3]) * LO_SCALE) };
  *(v4h*)(Ax + (size_t)row * KP +       (lane << 2)) = h;
  *(v4h*)(Ax + (size_t)row * KP + 256 + (lane << 2)) = l;
  if (lane == 0) partial[row] = ~0ull;
  if (row == 0 && lane == 0) out[LOSS_OFF] = 0.0f;
}

// ---------------- prep: c -> hi|slo + norms ----------------
__global__ __launch_bounds__(256) void vq_prep_c(
    const float* __restrict__ c, _Float16* __restrict__ Bc,
    float* __restrict__ cn) {
  const int w = threadIdx.x >> 6, lane = threadIdx.x & 63;
  const int row = blockIdx.x * 4 + w;
  const float4 v = *(const float4*)(c + (size_t)row * DIM + (lane << 2));
  v4h h = { (_Float16)v.x, (_Float16)v.y, (_Float16)v.z, (_Float16)v.w };
  v4h l = { (_Float16)((v.x - (float)h[0]) * LO_SCALE),
            (_Float16)((v.y - (float)h[1]) * LO_SCALE),
            (_Float16)((v.z - (float)h[2]) * LO_SCALE),
            (_Float16)((v.w - (float)h[3]) * LO_SCALE) };
  *(v4h*)(Bc + (size_t)row * KP +       (lane << 2)) = h;
  *(v4h*)(Bc + (size_t)row * KP + 256 + (lane << 2)) = l;
  float s = v.x * v.x + v.y * v.y + v.z * v.z + v.w * v.w;
  #pragma unroll
  for (int off = 32; off > 0; off >>= 1) s += __shfl_down(s, off);
  if (lane == 0) cn[row] = s;
}

// ---------------- main: fused split-f16 GEMM + argmin ----------------
// 128x128 tile, BK=64 halves, 4 waves (2x2 of 64x64), K_eff = 12 steps:
//  steps 0-3 : A hi  x B hi  -> acc0
//  steps 4-7 : A slo x B hi  -> acc1
//  steps 8-11: A hi  x B slo -> acc1
// dot = acc0 + acc1/2048 ; key = cn[col] - 2*dot ; u64 atomicMin per row.
__global__ __launch_bounds__(256) void vq_gemm_argmin(
    const _Float16* __restrict__ Ax, const _Float16* __restrict__ Bc,
    const float* __restrict__ cn, unsigned long long* __restrict__ partial) {
  __shared__ _Float16 As[128 * 64];   // 16 KB
  __shared__ _Float16 Bs[128 * 64];   // 16 KB

  const int tid = threadIdx.x, w = tid >> 6, lane = tid & 63;
  const int nt = blockIdx.x, mt = blockIdx.y;
  const int rowBase = mt * 128, colBase = nt * 128;
  const int wrow = (w >> 1) * 64, wcol = (w & 1) * 64;
  const int l15 = lane & 15, l4 = lane >> 4;

  // staging map: issue i: row = i*32 + w*8 + (lane>>3), 16B slot = lane&7
  const int st_row = (w << 3) + (lane >> 3);
  const int st_slot = lane & 7;

  f32x4 acc0[4][4], acc1[4][4];
  #pragma unroll
  for (int i = 0; i < 4; ++i)
    #pragma unroll
    for (int j = 0; j < 4; ++j) { acc0[i][j] = (f32x4)0.0f; acc1[i][j] = (f32x4)0.0f; }

  for (int step = 0; step < 12; ++step) {
    const int pass = step >> 2, kc = step & 3;
    const int a_off = (pass == 1 ? 256 : 0) + kc * 64;
    const int b_off = (pass == 2 ? 256 : 0) + kc * 64;
    __syncthreads();   // prior step's ds_reads complete before overwrite
    #pragma unroll
    for (int i = 0; i < 4; ++i) {
      const int r = (i << 5) + st_row;
      const int s = st_slot ^ (r & 7);    // source-side swizzle (lds dest linear)
      GLOAD_LDS16(Ax + (size_t)(rowBase + r) * KP + a_off + s * 8,
                  &As[((i << 5) + (w << 3)) * 64]);
      GLOAD_LDS16(Bc + (size_t)(colBase + r) * KP + b_off + s * 8,
                  &Bs[((i << 5) + (w << 3)) * 64]);
    }
    __syncthreads();   // vmcnt(0) drained before barrier by compiler

    #pragma unroll
    for (int ks = 0; ks < 2; ++ks) {
      v8h a[4], b[4];
      #pragma unroll
      for (int mi = 0; mi < 4; ++mi) {
        const int r = wrow + mi * 16 + l15;            // A row (M)
        const int slot = ((ks << 2) + l4) ^ (r & 7);   // swizzled 16B slot
        a[mi] = *(const v8h*)&As[r * 64 + slot * 8];
      }
      #pragma unroll
      for (int ni = 0; ni < 4; ++ni) {
        const int cc = wcol + ni * 16 + l15;           // B col (N)
        const int slot = ((ks << 2) + l4) ^ (cc & 7);
        b[ni] = *(const v8h*)&Bs[cc * 64 + slot * 8];
      }
      if (step < 4) {
        #pragma unroll
        for (int mi = 0; mi < 4; ++mi)
          #pragma unroll
          for (int ni = 0; ni < 4; ++ni)
            acc0[mi][ni] = __builtin_amdgcn_mfma_f32_16x16x32_f16(
                a[mi], b[ni], acc0[mi][ni], 0, 0, 0);
      } else {
        #pragma unroll
        for (int mi = 0; mi < 4; ++mi)
          #pragma unroll
          for (int ni = 0; ni < 4; ++ni)
            acc1[mi][ni] = __builtin_amdgcn_mfma_f32_16x16x32_f16(
                a[mi], b[ni], acc1[mi][ni], 0, 0, 0);
      }
    }
  }

  // ---- epilogue: key = cn - 2*(acc0 + acc1/2048), per-row u64 argmin ----
  // C/D layout (16x16): col = lane&15, row = (lane>>4)*4 + reg
  unsigned long long bestp[4][4];
  #pragma unroll
  for (int mi = 0; mi < 4; ++mi)
    #pragma unroll
    for (int r = 0; r < 4; ++r) bestp[mi][r] = ~0ull;

  #pragma unroll
  for (int ni = 0; ni < 4; ++ni) {
    const int col = colBase + wcol + ni * 16 + l15;
    const float cnv = cn[col];
    #pragma unroll
    for (int mi = 0; mi < 4; ++mi)
      #pragma unroll
      for (int r = 0; r < 4; ++r) {
        const float dot = acc0[mi][ni][r] + acc1[mi][ni][r] * (1.0f / LO_SCALE);
        const float d = fmaf(-2.0f, dot, cnv);
        unsigned kb = __float_as_uint(d);
        kb = (kb & 0x80000000u) ? ~kb : (kb | 0x80000000u);   // monotone map
        const unsigned long long p = ((unsigned long long)kb << 32) | (unsigned)col;
        if (p < bestp[mi][r]) bestp[mi][r] = p;
      }
  }
  // reduce across the 16 lanes holding the same rows
  #pragma unroll
  for (int off = 1; off < 16; off <<= 1)
    #pragma unroll
    for (int mi = 0; mi < 4; ++mi)
      #pragma unroll
      for (int r = 0; r < 4; ++r) {
        const unsigned long long o = __shfl_xor(bestp[mi][r], off);
        if (o < bestp[mi][r]) bestp[mi][r] = o;
      }
  // one atomic per lane: lane (l&15)==mi*4+r publishes row (static indices only)
  #pragma unroll
  for (int mi = 0; mi < 4; ++mi)
    #pragma unroll
    for (int r = 0; r < 4; ++r)
      if (l15 == mi * 4 + r) {
        const int grow = rowBase + wrow + mi * 16 + (l4 << 2) + r;
        atomicMin(&partial[grow], bestp[mi][r]);
      }
}

// ---------------- finish: gather + loss + index output ----------------
__global__ __launch_bounds__(256) void vq_finish(
    const float* __restrict__ x, const float* __restrict__ c,
    const unsigned long long* __restrict__ partial, float* __restrict__ out) {
  const int w = threadIdx.x >> 6, lane = threadIdx.x & 63;
  const int row = blockIdx.x * 4 + w;
  const int idx = (int)(partial[row] & 0xFFFFFFFFull);
  const float4 q = *(const float4*)(c + (size_t)idx * DIM + (lane << 2));
  const float4 v = *(const float4*)(x + (size_t)row * DIM + (lane << 2));
  *(float4*)(out + (size_t)row * DIM + (lane << 2)) = q;   // x_q_out == x_q
  const float dx = q.x - v.x, dy = q.y - v.y, dz = q.z - v.z, dw = q.w - v.w;
  float s = dx * dx + dy * dy + dz * dz + dw * dw;
  #pragma unroll
  for (int off = 32; off > 0; off >>= 1) s += __shfl_down(s, off);
  if (lane == 0) {
    atomicAdd(&out[LOSS_OFF], s * (1.25f / 8388608.0f));   // (1+BETA)*mean
    out[IDX_OFF + row] = (float)idx;
  }
}

extern "C" void kernel_launch(void* const* d_in, const int* in_sizes, int n_in,
                              void* d_out, int out_size, void* d_ws, size_t ws_size,
                              hipStream_t stream) {
  const float* x = (const float*)d_in[0];
  const float* c = (const float*)d_in[1];
  float* out = (float*)d_out;
  char* ws = (char*)d_ws;
  _Float16* Ax = (_Float16*)ws;
  _Float16* Bc = (_Float16*)(ws + 33554432);
  float*    cn = (float*)(ws + 41943040);
  unsigned long long* partial = (unsigned long long*)(ws + 41975808);

  vq_prep_x<<<BATCH / 4, 256, 0, stream>>>(x, Ax, partial, out);
  vq_prep_c<<<NE / 4,    256, 0, stream>>>(c, Bc, cn);
  dim3 grid(NE / 128, BATCH / 128, 1);   // x = N-tile (fast) -> A-panel L2 reuse
  vq_gemm_argmin<<<grid, 256, 0, stream>>>(Ax, Bc, cn, partial);
  vq_finish<<<BATCH / 4, 256, 0, stream>>>(x, c, partial, out);
}

// Round 4
// 735.739 us; speedup vs baseline: 3.6452x; 1.5463x over previous
//
#include <hip/hip_runtime.h>
#include <hip/hip_fp16.h>
#include <stdint.h>

#define BATCH 32768
#define NE    8192
#define DIM   256
#define KP    512            // packed [hi(256) | slo(256)] halves per row
#define LOSS_OFF 8388608     // 32768*256
#define IDX_OFF  8388609
#define LO_SCALE 2048.0f

typedef _Float16 v8h  __attribute__((ext_vector_type(8)));
typedef _Float16 v4h  __attribute__((ext_vector_type(4)));
typedef float    f32x4 __attribute__((ext_vector_type(4)));

// async global->LDS, 16B per lane; LDS dest = wave-uniform base + lane*16
#define GLOAD_LDS16(g, l) __builtin_amdgcn_global_load_lds( \
    (const __attribute__((address_space(1))) void*)(g),     \
    (__attribute__((address_space(3))) void*)(l), 16, 0, 0)

// ---- ws layout (bytes) ----
// Ax  f16 [BATCH][512]  @ 0          (33554432)
// Bc  f16 [NE][512]     @ 33554432   (8388608)
// cn  f32 [NE]          @ 41943040   (32768)
// part u64 [BATCH]      @ 41975808   (262144)   total ~40.3 MB

// ---------------- prep: x -> hi|slo, init partial/loss ----------------
__global__ __launch_bounds__(256) void vq_prep_x(
    const float* __restrict__ x, _Float16* __restrict__ Ax,
    unsigned long long* __restrict__ partial, float* __restrict__ out) {
  const int w = threadIdx.x >> 6, lane = threadIdx.x & 63;
  const int row = blockIdx.x * 4 + w;
  const float4 v = *(const float4*)(x + (size_t)row * DIM + (lane << 2));
  v4h h = { (_Float16)v.x, (_Float16)v.y, (_Float16)v.z, (_Float16)v.w };
  v4h l = { (_Float16)((v.x - (float)h[0]) * LO_SCALE),
            (_Float16)((v.y - (float)h[1]) * LO_SCALE),
            (_Float16)((v.z - (float)h[2]) * LO_SCALE),
            (_Float16)((v.w - (float)h[3]) * LO_SCALE) };
  *(v4h*)(Ax + (size_t)row * KP +       (lane << 2)) = h;
  *(v4h*)(Ax + (size_t)row * KP + 256 + (lane << 2)) = l;
  if (lane == 0) partial[row] = ~0ull;
  if (row == 0 && lane == 0) out[LOSS_OFF] = 0.0f;
}

// ---------------- prep: c -> hi|slo + norms ----------------
__global__ __launch_bounds__(256) void vq_prep_c(
    const float* __restrict__ c, _Float16* __restrict__ Bc,
    float* __restrict__ cn) {
  const int w = threadIdx.x >> 6, lane = threadIdx.x & 63;
  const int row = blockIdx.x * 4 + w;
  const float4 v = *(const float4*)(c + (size_t)row * DIM + (lane << 2));
  v4h h = { (_Float16)v.x, (_Float16)v.y, (_Float16)v.z, (_Float16)v.w };
  v4h l = { (_Float16)((v.x - (float)h[0]) * LO_SCALE),
            (_Float16)((v.y - (float)h[1]) * LO_SCALE),
            (_Float16)((v.z - (float)h[2]) * LO_SCALE),
            (_Float16)((v.w - (float)h[3]) * LO_SCALE) };
  *(v4h*)(Bc + (size_t)row * KP +       (lane << 2)) = h;
  *(v4h*)(Bc + (size_t)row * KP + 256 + (lane << 2)) = l;
  float s = v.x * v.x + v.y * v.y + v.z * v.z + v.w * v.w;
  #pragma unroll
  for (int off = 32; off > 0; off >>= 1) s += __shfl_down(s, off);
  if (lane == 0) cn[row] = s;
}

// ---------------- main: fused split-f16 GEMM + argmin ----------------
// 128x128 tile, BK=64 halves, 4 waves (2x2 of 64x64), K_eff = 12 steps:
//  steps 0-3 : A hi  x B hi  -> acc0
//  steps 4-7 : A slo x B hi  -> acc1
//  steps 8-11: A hi  x B slo -> acc1
// dot = acc0 + acc1/2048 ; key = cn[col] - 2*dot ; u64 atomicMin per row.
__global__ __launch_bounds__(256) void vq_gemm_argmin(
    const _Float16* __restrict__ Ax, const _Float16* __restrict__ Bc,
    const float* __restrict__ cn, unsigned long long* __restrict__ partial) {
  __shared__ _Float16 As[128 * 64];   // 16 KB
  __shared__ _Float16 Bs[128 * 64];   // 16 KB

  const int tid = threadIdx.x, w = tid >> 6, lane = tid & 63;
  const int nt = blockIdx.x, mt = blockIdx.y;
  const int rowBase = mt * 128, colBase = nt * 128;
  const int wrow = (w >> 1) * 64, wcol = (w & 1) * 64;
  const int l15 = lane & 15, l4 = lane >> 4;

  // staging map: issue i: row = i*32 + w*8 + (lane>>3), 16B slot = lane&7
  const int st_row = (w << 3) + (lane >> 3);
  const int st_slot = lane & 7;

  f32x4 acc0[4][4], acc1[4][4];
  #pragma unroll
  for (int i = 0; i < 4; ++i)
    #pragma unroll
    for (int j = 0; j < 4; ++j) { acc0[i][j] = (f32x4)0.0f; acc1[i][j] = (f32x4)0.0f; }

  for (int step = 0; step < 12; ++step) {
    const int pass = step >> 2, kc = step & 3;
    const int a_off = (pass == 1 ? 256 : 0) + kc * 64;
    const int b_off = (pass == 2 ? 256 : 0) + kc * 64;
    __syncthreads();   // prior step's ds_reads complete before overwrite
    #pragma unroll
    for (int i = 0; i < 4; ++i) {
      const int r = (i << 5) + st_row;
      const int s = st_slot ^ (r & 7);    // source-side swizzle (lds dest linear)
      GLOAD_LDS16(Ax + (size_t)(rowBase + r) * KP + a_off + s * 8,
                  &As[((i << 5) + (w << 3)) * 64]);
      GLOAD_LDS16(Bc + (size_t)(colBase + r) * KP + b_off + s * 8,
                  &Bs[((i << 5) + (w << 3)) * 64]);
    }
    __syncthreads();   // vmcnt(0) drained before barrier by compiler

    #pragma unroll
    for (int ks = 0; ks < 2; ++ks) {
      v8h a[4], b[4];
      #pragma unroll
      for (int mi = 0; mi < 4; ++mi) {
        const int r = wrow + mi * 16 + l15;            // A row (M)
        const int slot = ((ks << 2) + l4) ^ (r & 7);   // swizzled 16B slot
        a[mi] = *(const v8h*)&As[r * 64 + slot * 8];
      }
      #pragma unroll
      for (int ni = 0; ni < 4; ++ni) {
        const int cc = wcol + ni * 16 + l15;           // B col (N)
        const int slot = ((ks << 2) + l4) ^ (cc & 7);
        b[ni] = *(const v8h*)&Bs[cc * 64 + slot * 8];
      }
      if (step < 4) {
        #pragma unroll
        for (int mi = 0; mi < 4; ++mi)
          #pragma unroll
          for (int ni = 0; ni < 4; ++ni)
            acc0[mi][ni] = __builtin_amdgcn_mfma_f32_16x16x32_f16(
                a[mi], b[ni], acc0[mi][ni], 0, 0, 0);
      } else {
        #pragma unroll
        for (int mi = 0; mi < 4; ++mi)
          #pragma unroll
          for (int ni = 0; ni < 4; ++ni)
            acc1[mi][ni] = __builtin_amdgcn_mfma_f32_16x16x32_f16(
                a[mi], b[ni], acc1[mi][ni], 0, 0, 0);
      }
    }
  }

  // ---- epilogue: key = cn - 2*(acc0 + acc1/2048), per-row u64 argmin ----
  // C/D layout (16x16): col = lane&15, row = (lane>>4)*4 + reg
  unsigned long long bestp[4][4];
  #pragma unroll
  for (int mi = 0; mi < 4; ++mi)
    #pragma unroll
    for (int r = 0; r < 4; ++r) bestp[mi][r] = ~0ull;

  #pragma unroll
  for (int ni = 0; ni < 4; ++ni) {
    const int col = colBase + wcol + ni * 16 + l15;
    const float cnv = cn[col];
    #pragma unroll
    for (int mi = 0; mi < 4; ++mi)
      #pragma unroll
      for (int r = 0; r < 4; ++r) {
        const float dot = acc0[mi][ni][r] + acc1[mi][ni][r] * (1.0f / LO_SCALE);
        const float d = fmaf(-2.0f, dot, cnv);
        unsigned kb = __float_as_uint(d);
        kb = (kb & 0x80000000u) ? ~kb : (kb | 0x80000000u);   // monotone map
        const unsigned long long p = ((unsigned long long)kb << 32) | (unsigned)col;
        if (p < bestp[mi][r]) bestp[mi][r] = p;
      }
  }
  // reduce across the 16 lanes holding the same rows
  #pragma unroll
  for (int off = 1; off < 16; off <<= 1)
    #pragma unroll
    for (int mi = 0; mi < 4; ++mi)
      #pragma unroll
      for (int r = 0; r < 4; ++r) {
        const unsigned long long o = __shfl_xor(bestp[mi][r], off);
        if (o < bestp[mi][r]) bestp[mi][r] = o;
      }
  // one atomic per lane: lane (l&15)==mi*4+r publishes row (static indices only)
  #pragma unroll
  for (int mi = 0; mi < 4; ++mi)
    #pragma unroll
    for (int r = 0; r < 4; ++r)
      if (l15 == mi * 4 + r) {
        const int grow = rowBase + wrow + mi * 16 + (l4 << 2) + r;
        atomicMin(&partial[grow], bestp[mi][r]);
      }
}

// ---------------- finish: gather + loss + index output ----------------
// 256 blocks x 256 threads; block handles 128 rows (wave w: rows i*4+w).
// Loss: per-lane register accumulation across rows -> one shuffle reduce
// per wave -> LDS combine -> ONE atomicAdd per block (256 total, not 32768).
__global__ __launch_bounds__(256) void vq_finish(
    const float* __restrict__ x, const float* __restrict__ c,
    const unsigned long long* __restrict__ partial, float* __restrict__ out) {
  __shared__ float red[4];
  const int w = threadIdx.x >> 6, lane = threadIdx.x & 63;
  float s = 0.0f;
  #pragma unroll 4
  for (int i = 0; i < 32; ++i) {
    const int row = blockIdx.x * 128 + i * 4 + w;
    const int idx = (int)(partial[row] & 0xFFFFFFFFull);
    const float4 q = *(const float4*)(c + (size_t)idx * DIM + (lane << 2));
    const float4 v = *(const float4*)(x + (size_t)row * DIM + (lane << 2));
    *(float4*)(out + (size_t)row * DIM + (lane << 2)) = q;   // x_q_out == x_q
    const float dx = q.x - v.x, dy = q.y - v.y, dz = q.z - v.z, dw = q.w - v.w;
    s += dx * dx + dy * dy + dz * dz + dw * dw;
    if (lane == 0) out[IDX_OFF + row] = (float)idx;
  }
  #pragma unroll
  for (int off = 32; off > 0; off >>= 1) s += __shfl_down(s, off);
  if (lane == 0) red[w] = s;
  __syncthreads();
  if (threadIdx.x == 0) {
    const float t = red[0] + red[1] + red[2] + red[3];
    atomicAdd(&out[LOSS_OFF], t * (1.25f / 8388608.0f));   // (1+BETA)*mean
  }
}

extern "C" void kernel_launch(void* const* d_in, const int* in_sizes, int n_in,
                              void* d_out, int out_size, void* d_ws, size_t ws_size,
                              hipStream_t stream) {
  const float* x = (const float*)d_in[0];
  const float* c = (const float*)d_in[1];
  float* out = (float*)d_out;
  char* ws = (char*)d_ws;
  _Float16* Ax = (_Float16*)ws;
  _Float16* Bc = (_Float16*)(ws + 33554432);
  float*    cn = (float*)(ws + 41943040);
  unsigned long long* partial = (unsigned long long*)(ws + 41975808);

  vq_prep_x<<<BATCH / 4, 256, 0, stream>>>(x, Ax, partial, out);
  vq_prep_c<<<NE / 4,    256, 0, stream>>>(c, Bc, cn);
  dim3 grid(NE / 128, BATCH / 128, 1);   // x = N-tile (fast) -> A-panel L2 reuse
  vq_gemm_argmin<<<grid, 256, 0, stream>>>(Ax, Bc, cn, partial);
  vq_finish<<<BATCH / 128, 256, 0, stream>>>(x, c, partial, out);
}

// Round 5
// 459.746 us; speedup vs baseline: 5.8335x; 1.6003x over previous
//
#include <hip/hip_runtime.h>
#include <hip/hip_fp16.h>
#include <stdint.h>

#define BATCH 32768
#define NE    8192
#define DIM   256
#define LOSS_OFF 8388608     // 32768*256
#define IDX_OFF  8388609
#define MARGIN 0.25f         // ~17 sigma of hi*hi dist^2 error model

typedef _Float16 v8h  __attribute__((ext_vector_type(8)));
typedef _Float16 v4h  __attribute__((ext_vector_type(4)));
typedef float    f32x4 __attribute__((ext_vector_type(4)));
typedef unsigned long long ull;

// async global->LDS, 16B per lane; LDS dest = wave-uniform base + lane*16
#define GLOAD_LDS16(g, l) __builtin_amdgcn_global_load_lds( \
    (const __attribute__((address_space(1))) void*)(g),     \
    (__attribute__((address_space(3))) void*)(l), 16, 0, 0)

// ---- ws layout (bytes) ----
// Ahi  f16 [BATCH][256] @ 0         (16777216)
// Bhi  f16 [NE][256]    @ 16777216  ( 4194304)
// cn   f32 [NE]         @ 20971520  (   32768)
// xn   f32 [BATCH]      @ 21004288  (  131072)
// bidx i32 [BATCH]      @ 21135360  (  131072)
// cand u64 [BATCH][64][2] @ 21266432 (33554432)   total ~52.3 MB

// monotone map f32 -> u32 (order-preserving for <)
__device__ __forceinline__ unsigned enc_key(float f) {
  unsigned b = __float_as_uint(f);
  return (b & 0x80000000u) ? ~b : (b | 0x80000000u);
}
__device__ __forceinline__ float dec_key(unsigned kb) {
  return __uint_as_float((kb & 0x80000000u) ? (kb ^ 0x80000000u) : ~kb);
}

// ---------------- prep: x -> hi f16, row norms, loss zero ----------------
__global__ __launch_bounds__(256) void vq_prep_x(
    const float* __restrict__ x, _Float16* __restrict__ Ahi,
    float* __restrict__ xn, float* __restrict__ out) {
  const int w = threadIdx.x >> 6, lane = threadIdx.x & 63;
  const int row = blockIdx.x * 4 + w;
  const float4 v = *(const float4*)(x + (size_t)row * DIM + (lane << 2));
  v4h h = { (_Float16)v.x, (_Float16)v.y, (_Float16)v.z, (_Float16)v.w };
  *(v4h*)(Ahi + (size_t)row * DIM + (lane << 2)) = h;
  float s = v.x * v.x + v.y * v.y + v.z * v.z + v.w * v.w;
  #pragma unroll
  for (int off = 32; off > 0; off >>= 1) s += __shfl_down(s, off);
  if (lane == 0) xn[row] = s;
  if (row == 0 && lane == 0) out[LOSS_OFF] = 0.0f;
}

// ---------------- prep: c -> hi f16 + norms ----------------
__global__ __launch_bounds__(256) void vq_prep_c(
    const float* __restrict__ c, _Float16* __restrict__ Bhi,
    float* __restrict__ cn) {
  const int w = threadIdx.x >> 6, lane = threadIdx.x & 63;
  const int row = blockIdx.x * 4 + w;
  const float4 v = *(const float4*)(c + (size_t)row * DIM + (lane << 2));
  v4h h = { (_Float16)v.x, (_Float16)v.y, (_Float16)v.z, (_Float16)v.w };
  *(v4h*)(Bhi + (size_t)row * DIM + (lane << 2)) = h;
  float s = v.x * v.x + v.y * v.y + v.z * v.z + v.w * v.w;
  #pragma unroll
  for (int off = 32; off > 0; off >>= 1) s += __shfl_down(s, off);
  if (lane == 0) cn[row] = s;
}

// ---------------- stage 1: hi*hi GEMM + per-(row, 128-col-tile) top-2 ----
// 128x128 tile, K=256 halves in 4 BK=64 steps, double-buffered LDS.
// Waves = 4 M-quarters (32 rows each) x full 128 cols, so top-2 over the
// block's col-tile is wave-local. key = cn[col] - 2*dot (xn row-constant).
__global__ __launch_bounds__(256) void vq_gemm1(
    const _Float16* __restrict__ A, const _Float16* __restrict__ B,
    const float* __restrict__ cn, ull* __restrict__ cand) {
  __shared__ _Float16 As[2][128 * 64];   // 32 KB
  __shared__ _Float16 Bs[2][128 * 64];   // 32 KB

  const int tid = threadIdx.x, w = tid >> 6, lane = tid & 63;
  const int nt = blockIdx.x, mt = blockIdx.y;
  const int rowBase = mt * 128, colBase = nt * 128;
  const int l15 = lane & 15, l4 = lane >> 4;
  const int st_row = (w << 3) + (lane >> 3);   // wave w covers rows [w*8,w*8+8)
  const int st_slot = lane & 7;

  f32x4 acc[2][8];
  #pragma unroll
  for (int mi = 0; mi < 2; ++mi)
    #pragma unroll
    for (int ni = 0; ni < 8; ++ni) acc[mi][ni] = (f32x4)0.0f;

  auto STAGE = [&](int buf, int kc) {
    #pragma unroll
    for (int i = 0; i < 4; ++i) {
      const int r = (i << 5) + st_row;
      const int s = st_slot ^ (r & 7);   // source-side swizzle; LDS dest linear
      GLOAD_LDS16(A + (size_t)(rowBase + r) * DIM + kc * 64 + s * 8,
                  &As[buf][((i << 5) + (w << 3)) * 64]);
      GLOAD_LDS16(B + (size_t)(colBase + r) * DIM + kc * 64 + s * 8,
                  &Bs[buf][((i << 5) + (w << 3)) * 64]);
    }
  };

  STAGE(0, 0);
  __syncthreads();                       // buf0 landed (vmcnt drain + barrier)
  for (int kc = 0; kc < 4; ++kc) {
    const int cur = kc & 1;
    if (kc < 3) STAGE(cur ^ 1, kc + 1);  // issue next tile, hide under compute
    #pragma unroll
    for (int ks = 0; ks < 2; ++ks) {
      v8h a[2], b[8];
      #pragma unroll
      for (int mi = 0; mi < 2; ++mi) {
        const int r = (w << 5) + mi * 16 + l15;         // A row (M)
        const int slot = ((ks << 2) + l4) ^ (r & 7);
        a[mi] = *(const v8h*)&As[cur][r * 64 + slot * 8];
      }
      #pragma unroll
      for (int ni = 0; ni < 8; ++ni) {
        const int cc = ni * 16 + l15;                   // B col (N)
        const int slot = ((ks << 2) + l4) ^ (cc & 7);
        b[ni] = *(const v8h*)&Bs[cur][cc * 64 + slot * 8];
      }
      #pragma unroll
      for (int mi = 0; mi < 2; ++mi)
        #pragma unroll
        for (int ni = 0; ni < 8; ++ni)
          acc[mi][ni] = __builtin_amdgcn_mfma_f32_16x16x32_f16(
              a[mi], b[ni], acc[mi][ni], 0, 0, 0);
    }
    __syncthreads();   // drains this step's prefetch; next buf ready
  }

  // ---- epilogue: per-(mi,r) row, top-2 over the 128 cols, direct store ----
  #pragma unroll
  for (int mi = 0; mi < 2; ++mi)
    #pragma unroll
    for (int r = 0; r < 4; ++r) {
      ull f = ~0ull, s = ~0ull;
      #pragma unroll
      for (int ni = 0; ni < 8; ++ni) {
        const int col = colBase + ni * 16 + l15;
        const float key = fmaf(-2.0f, acc[mi][ni][r], cn[col]);
        const ull p = ((ull)enc_key(key) << 32) | (unsigned)col;
        if (p < f) { s = f; f = p; } else if (p < s) { s = p; }
      }
      #pragma unroll
      for (int off = 1; off < 16; off <<= 1) {   // merge sorted pairs, 16 lanes
        const ull of = __shfl_xor(f, off);
        const ull os = __shfl_xor(s, off);
        ull nf, ns;
        if (f <= of) { nf = f;  ns = (of < s ? of : s); }
        else         { nf = of; ns = (f < os ? f : os); }
        f = nf; s = ns;
      }
      if (l15 == ((mi << 2) | r)) {
        const int row = rowBase + (w << 5) + mi * 16 + (l4 << 2) + r;
        ull* dst = cand + ((size_t)row * 64 + nt) * 2;
        dst[0] = f; dst[1] = s;
      }
    }
}

// ---------------- stage 2: per-row margin test + exact refine ----------------
__global__ __launch_bounds__(256) void vq_refine(
    const ull* __restrict__ cand, const float* __restrict__ x,
    const float* __restrict__ c, const float* __restrict__ xn,
    const float* __restrict__ cn, int* __restrict__ bestIdx) {
  const int w = threadIdx.x >> 6, lane = threadIdx.x & 63;
  const int row = blockIdx.x * 4 + w;
  const ull pf = cand[((size_t)row * 64 + lane) * 2];
  const ull ps = cand[((size_t)row * 64 + lane) * 2 + 1];
  ull gb = pf;
  #pragma unroll
  for (int off = 1; off < 64; off <<= 1) { const ull o = __shfl_xor(gb, off); if (o < gb) gb = o; }
  const unsigned thr = enc_key(dec_key((unsigned)(gb >> 32)) + MARGIN);
  const ull m1 = __ballot((unsigned)(pf >> 32) <= thr);
  const ull m2 = __ballot((unsigned)(ps >> 32) <= thr);
  int winner;
  if (__popcll(m1) == 1 && m2 == 0ull) {
    winner = (int)(unsigned)(gb & 0xffffffffull);   // provably the argmin
  } else {
    const float4 xv = *(const float4*)(x + (size_t)row * DIM + (lane << 2));
    const float xnr = xn[row];
    float bd = 3.4e38f; int bi = 0x7fffffff;
    for (int pass = 0; pass < 2; ++pass) {
      ull m = (pass == 0) ? m1 : m2;
      while (m) {
        const int src = __ffsll((long long)m) - 1; m &= m - 1;
        const ull p = __shfl((pass == 0) ? pf : ps, src);
        const int idx = (int)(unsigned)(p & 0xffffffffull);
        const float4 cv = *(const float4*)(c + (size_t)idx * DIM + (lane << 2));
        float dsum = xv.x * cv.x + xv.y * cv.y + xv.z * cv.z + xv.w * cv.w;
        #pragma unroll
        for (int off = 1; off < 64; off <<= 1) dsum += __shfl_xor(dsum, off);
        const float d = xnr + cn[idx] - 2.0f * dsum;   // round-2-proven formula
        if (d < bd || (d == bd && idx < bi)) { bd = d; bi = idx; }
      }
    }
    winner = bi;
  }
  if (lane == 0) bestIdx[row] = winner;
}

// ---------------- finish: gather + loss + index output ----------------
__global__ __launch_bounds__(256) void vq_finish(
    const float* __restrict__ x, const float* __restrict__ c,
    const int* __restrict__ bestIdx, float* __restrict__ out) {
  __shared__ float red[4];
  const int w = threadIdx.x >> 6, lane = threadIdx.x & 63;
  float s = 0.0f;
  #pragma unroll 4
  for (int i = 0; i < 32; ++i) {
    const int row = blockIdx.x * 128 + i * 4 + w;
    const int idx = bestIdx[row];
    const float4 q = *(const float4*)(c + (size_t)idx * DIM + (lane << 2));
    const float4 v = *(const float4*)(x + (size_t)row * DIM + (lane << 2));
    *(float4*)(out + (size_t)row * DIM + (lane << 2)) = q;   // x_q_out == x_q
    const float dx = q.x - v.x, dy = q.y - v.y, dz = q.z - v.z, dw = q.w - v.w;
    s += dx * dx + dy * dy + dz * dz + dw * dw;
    if (lane == 0) out[IDX_OFF + row] = (float)idx;
  }
  #pragma unroll
  for (int off = 32; off > 0; off >>= 1) s += __shfl_down(s, off);
  if (lane == 0) red[w] = s;
  __syncthreads();
  if (threadIdx.x == 0) {
    const float t = red[0] + red[1] + red[2] + red[3];
    atomicAdd(&out[LOSS_OFF], t * (1.25f / 8388608.0f));   // (1+BETA)*mean
  }
}

extern "C" void kernel_launch(void* const* d_in, const int* in_sizes, int n_in,
                              void* d_out, int out_size, void* d_ws, size_t ws_size,
                              hipStream_t stream) {
  const float* x = (const float*)d_in[0];
  const float* c = (const float*)d_in[1];
  float* out = (float*)d_out;
  char* ws = (char*)d_ws;
  _Float16* Ahi = (_Float16*)ws;
  _Float16* Bhi = (_Float16*)(ws + 16777216);
  float*    cn  = (float*)(ws + 20971520);
  float*    xn  = (float*)(ws + 21004288);
  int*  bestIdx = (int*)(ws + 21135360);
  ull*     cand = (ull*)(ws + 21266432);

  vq_prep_x<<<BATCH / 4, 256, 0, stream>>>(x, Ahi, xn, out);
  vq_prep_c<<<NE / 4,    256, 0, stream>>>(c, Bhi, cn);
  dim3 grid(NE / 128, BATCH / 128, 1);   // x = col-tile fast -> A-panel L2 reuse
  vq_gemm1 <<<grid, 256, 0, stream>>>(Ahi, Bhi, cn, cand);
  vq_refine<<<BATCH / 4, 256, 0, stream>>>(cand, x, c, xn, cn, bestIdx);
  vq_finish<<<BATCH / 128, 256, 0, stream>>>(x, c, bestIdx, out);
}